// Round 16
// baseline (462.037 us; speedup 1.0000x reference)
//
#include <hip/hip_runtime.h>
#include <stdint.h>

// Problem constants (N,C,H,W)=(4,96,96,96), half-res 48x48
#define BN_ 4
#define CC 96
#define HF 96
#define WF 96
#define HS 48
#define WS 48
#define LL 2304      // HS*WS
#define J2 1536      // CC*16 (4x4 raw filter feature dim)
#define NEG10 (-1.0e10f)
#define NLS 32       // l-splits for colstat partials (72 l each)

typedef __attribute__((ext_vector_type(8))) _Float16 half8v;
typedef __attribute__((ext_vector_type(4))) float float4v;
typedef float float4u __attribute__((ext_vector_type(4), aligned(4)));  // unaligned-capable

__device__ __forceinline__ int Tswap(int f) { return (f % 48) * 48 + f / 48; }

__device__ __forceinline__ unsigned short f2h(float f) {
    _Float16 h = (_Float16)f;
    return __builtin_bit_cast(unsigned short, h);
}
__device__ __forceinline__ float h2f(unsigned short u) {
    return (float)__builtin_bit_cast(_Float16, u);
}

typedef const __attribute__((address_space(1))) uint32_t* gas_ptr;
typedef __attribute__((address_space(3))) uint32_t* las_ptr;
__device__ __forceinline__ void gload16(const void* g, void* l) {
    __builtin_amdgcn_global_load_lds((gas_ptr)g, (las_ptr)l, 16, 0, 0);
}

// ---- channel-sum-of-squares of strided context: ssum[n][i][j] ----
__global__ void ssum_kernel(const float* __restrict__ ctx, float* __restrict__ ssum) {
    int idx = blockIdx.x * 256 + threadIdx.x;
    if (idx >= BN_ * HS * WS) return;
    int j = idx % WS, i = (idx / WS) % HS, n = idx / (WS * HS);
    float s = 0.f;
    for (int c = 0; c < CC; ++c) {
        float v = ctx[((size_t)(n * CC + c) * HF + 2 * i) * WF + 2 * j];
        s += v * v;
    }
    ssum[idx] = s;
}

// ---- merged: invn[n][l] and maskadd[n][l] ----
__global__ void invnmask_kernel(const float* __restrict__ ssum, const float* __restrict__ mask,
                                float* __restrict__ invn, float* __restrict__ maskadd) {
    int idx = blockIdx.x * 256 + threadIdx.x;
    if (idx >= BN_ * LL) return;
    int l = idx % LL, n = idx / LL;
    int i0 = l / WS, j0 = l % WS;
    float s = 0.f, ms = 0.f;
    for (int dy = -1; dy <= 1; ++dy)
        for (int dx = -1; dx <= 1; ++dx) {
            int i = i0 + dy, j = j0 + dx;
            if (i >= 0 && i < HS && j >= 0 && j < WS) {
                s += ssum[(n * HS + i) * WS + j];
                ms += mask[(size_t)n * HF * WF + (2 * i) * WF + 2 * j];
            }
        }
    invn[idx] = 1.f / fmaxf(sqrtf(s), 1e-4f);
    maskadd[idx] = (ms > 0.f) ? NEG10 : 0.f;
}

// ---- strided slice + f16 hi/lo split for BOTH tensors: dst[n][u][c] (c-major) ----
__global__ void slice_split2(const float* __restrict__ ctx, const float* __restrict__ x,
                             unsigned short* __restrict__ cs_hi, unsigned short* __restrict__ cs_lo,
                             unsigned short* __restrict__ xs_hi, unsigned short* __restrict__ xs_lo) {
    int idx = blockIdx.x * 256 + threadIdx.x;
    if (idx >= BN_ * LL * CC) return;
    const float* src = blockIdx.y ? x : ctx;
    unsigned short* hi = blockIdx.y ? xs_hi : cs_hi;
    unsigned short* lo = blockIdx.y ? xs_lo : cs_lo;
    int c = idx % CC;
    int u = (idx / CC) % LL;
    int n = idx / (CC * LL);
    int i = u / WS, j = u % WS;
    float v = src[((size_t)(n * CC + c) * HF + 2 * i) * WF + 2 * j];
    unsigned short h = f2h(v);
    hi[idx] = h;
    lo[idx] = f2h(v - h2f(h));
}

// ---- raw filter, transposed, f16: RF[n][j][l] ----
__global__ void rf_split(const float* __restrict__ ctx, unsigned short* __restrict__ hf) {
    int idx = blockIdx.x * 256 + threadIdx.x;
    if (idx >= BN_ * J2 * LL) return;
    int l = idx % LL;
    int j = (idx / LL) % J2;
    int n = idx / (LL * J2);
    int c = j >> 4, ky = (j >> 2) & 3, kx = j & 3;
    int y = 2 * (l / WS) + ky - 1;
    int x = 2 * (l % WS) + kx - 1;
    float v = 0.f;
    if (y >= 0 && y < HF && x >= 0 && x < WF)
        v = ctx[((size_t)(n * CC + c) * HF + y) * WF + x];
    hf[idx] = f2h(v);
}

// ---- f16 MFMA GEMM (TERMS=3 split, BK=32, single-buffer): C fp32 ----
__global__ __launch_bounds__(256, 4) void gemm_split3(
    const unsigned short* __restrict__ Ah_, const unsigned short* __restrict__ Al_,
    const unsigned short* __restrict__ Bh_, const unsigned short* __restrict__ Bl_,
    float* __restrict__ Cout, int M_, int N_, int K_, int nbx, int nby)
{
    __shared__ unsigned short lds[4][128][32];

    int wg = blockIdx.x;
    int wgid = (wg & 7) * (gridDim.x >> 3) + (wg >> 3);
    int bx = wgid % nbx;
    int t1 = wgid / nbx;
    int by = t1 % nby;
    int bz = t1 / nby;
    const int m0 = by * 128, n0 = bx * 128;
    const int t = threadIdx.x;

    const size_t sA = (size_t)M_ * K_, sB = (size_t)N_ * K_;
    const unsigned short* Ah = Ah_ + (size_t)bz * sA;
    const unsigned short* Al = Al_ + (size_t)bz * sA;
    const unsigned short* Bh = Bh_ + (size_t)bz * sB;
    const unsigned short* Bl = Bl_ + (size_t)bz * sB;

    const int rloc = t >> 2;
    const int sst = t & 3;
    const int kg = sst ^ ((rloc >> 1) & 3);
    const size_t offA0 = (size_t)(m0 + rloc) * K_ + kg * 8;
    const size_t offA1 = (size_t)(m0 + 64 + rloc) * K_ + kg * 8;
    const size_t offB0 = (size_t)(n0 + rloc) * K_ + kg * 8;
    const size_t offB1 = (size_t)(n0 + 64 + rloc) * K_ + kg * 8;
    const unsigned short* gp0 = Ah + offA0;
    const unsigned short* gp1 = Ah + offA1;
    const unsigned short* gp2 = Al + offA0;
    const unsigned short* gp3 = Al + offA1;
    const unsigned short* gp4 = Bh + offB0;
    const unsigned short* gp5 = Bh + offB1;
    const unsigned short* gp6 = Bl + offB0;
    const unsigned short* gp7 = Bl + offB1;
    unsigned short* lp0 = &lds[0][rloc][sst * 8];
    unsigned short* lp1 = &lds[0][64 + rloc][sst * 8];
    unsigned short* lp2 = &lds[1][rloc][sst * 8];
    unsigned short* lp3 = &lds[1][64 + rloc][sst * 8];
    unsigned short* lp4 = &lds[2][rloc][sst * 8];
    unsigned short* lp5 = &lds[2][64 + rloc][sst * 8];
    unsigned short* lp6 = &lds[3][rloc][sst * 8];
    unsigned short* lp7 = &lds[3][64 + rloc][sst * 8];

    const int lane = t & 63;
    const int w = t >> 6, wr = w >> 1, wc = w & 1;
    const int lr = lane & 15, lg = lane >> 4;

    float4v acc[4][4] = {};
    const int nt = K_ / 32;

    for (int kt = 0; kt < nt; ++kt) {
        __syncthreads();
        gload16(gp0, lp0); gload16(gp1, lp1);
        gload16(gp2, lp2); gload16(gp3, lp3);
        gload16(gp4, lp4); gload16(gp5, lp5);
        gload16(gp6, lp6); gload16(gp7, lp7);
        gp0 += 32; gp1 += 32; gp2 += 32; gp3 += 32;
        gp4 += 32; gp5 += 32; gp6 += 32; gp7 += 32;
        __syncthreads();

        half8v bh[4], bl[4];
#pragma unroll
        for (int j = 0; j < 4; ++j) {
            int row = wc * 64 + j * 16 + lr;
            int s = (lg ^ ((row >> 1) & 3)) * 8;
            bh[j] = *(const half8v*)&lds[2][row][s];
            bl[j] = *(const half8v*)&lds[3][row][s];
        }
#pragma unroll
        for (int i = 0; i < 4; ++i) {
            int row = wr * 64 + i * 16 + lr;
            int s = (lg ^ ((row >> 1) & 3)) * 8;
            half8v ah = *(const half8v*)&lds[0][row][s];
            half8v al = *(const half8v*)&lds[1][row][s];
#pragma unroll
            for (int j = 0; j < 4; ++j) {
                acc[i][j] = __builtin_amdgcn_mfma_f32_16x16x32_f16(ah, bh[j], acc[i][j], 0, 0, 0);
                acc[i][j] = __builtin_amdgcn_mfma_f32_16x16x32_f16(ah, bl[j], acc[i][j], 0, 0, 0);
                acc[i][j] = __builtin_amdgcn_mfma_f32_16x16x32_f16(al, bh[j], acc[i][j], 0, 0, 0);
            }
        }
    }

    float* Cb = Cout + (size_t)bz * M_ * N_;
#pragma unroll
    for (int i = 0; i < 4; ++i) {
        int mb = m0 + wr * 64 + i * 16 + lg * 4;
#pragma unroll
        for (int j = 0; j < 4; ++j) {
            int nn = n0 + wc * 64 + j * 16 + lr;
#pragma unroll
            for (int r = 0; r < 4; ++r)
                Cb[(size_t)(mb + r) * N_ + nn] = acc[i][j][r];
        }
    }
}

// ---- f16 MFMA GEMM (1-term, BK=64, single-buffer 1-phase): C f16 ----
__global__ __launch_bounds__(256, 4) void gemm_k64(
    const unsigned short* __restrict__ Ah_, const unsigned short* __restrict__ Bh_,
    unsigned short* __restrict__ Cout, int M_, int N_, int K_, int nbx, int nby)
{
    __shared__ unsigned short lds[2][128][64];

    int wg = blockIdx.x;
    int wgid = (wg & 7) * (gridDim.x >> 3) + (wg >> 3);
    int bx = wgid % nbx;
    int t1 = wgid / nbx;
    int by = t1 % nby;
    int bz = t1 / nby;
    const int m0 = by * 128, n0 = bx * 128;
    const int t = threadIdx.x;

    const unsigned short* Ah = Ah_ + (size_t)bz * M_ * K_;
    const unsigned short* Bh = Bh_ + (size_t)bz * N_ * K_;

    const unsigned short* gpA[4];
    const unsigned short* gpB[4];
    int lo[4];
#pragma unroll
    for (int rep = 0; rep < 4; ++rep) {
        int slot = t + rep * 256;
        int row = slot >> 3, sc = slot & 7;
        int kg = sc ^ (row & 7);                   // pre-swizzled global source
        gpA[rep] = Ah + (size_t)(m0 + row) * K_ + kg * 8;
        gpB[rep] = Bh + (size_t)(n0 + row) * K_ + kg * 8;
        lo[rep] = row * 64 + sc * 8;               // linear LDS dest (shorts)
    }

    const int lane = t & 63;
    const int w = t >> 6, wr = w >> 1, wc = w & 1;
    const int lr = lane & 15, lg = lane >> 4;

    float4v acc[4][4] = {};
    const int nt = K_ / 64;
    unsigned short* LA = &lds[0][0][0];
    unsigned short* LB = &lds[1][0][0];

    for (int kt = 0; kt < nt; ++kt) {
        __syncthreads();
#pragma unroll
        for (int rep = 0; rep < 4; ++rep) {
            gload16(gpA[rep], LA + lo[rep]);
            gload16(gpB[rep], LB + lo[rep]);
            gpA[rep] += 64; gpB[rep] += 64;
        }
        __syncthreads();
#pragma unroll
        for (int kk = 0; kk < 2; ++kk) {
            half8v bh[4];
#pragma unroll
            for (int j = 0; j < 4; ++j) {
                int row = wc * 64 + j * 16 + lr;
                int sc = (kk * 4 + lg) ^ (row & 7);    // same involution on read side
                bh[j] = *(const half8v*)&lds[1][row][sc * 8];
            }
#pragma unroll
            for (int i = 0; i < 4; ++i) {
                int row = wr * 64 + i * 16 + lr;
                int sc = (kk * 4 + lg) ^ (row & 7);
                half8v ah = *(const half8v*)&lds[0][row][sc * 8];
#pragma unroll
                for (int j = 0; j < 4; ++j)
                    acc[i][j] = __builtin_amdgcn_mfma_f32_16x16x32_f16(ah, bh[j], acc[i][j], 0, 0, 0);
            }
        }
    }

    unsigned short* Gb = Cout + (size_t)bz * M_ * N_;
#pragma unroll
    for (int i = 0; i < 4; ++i) {
        int mb = m0 + wr * 64 + i * 16 + lg * 4;
#pragma unroll
        for (int j = 0; j < 4; ++j) {
            int nn = n0 + wc * 64 + j * 16 + lr;
#pragma unroll
            for (int r = 0; r < 4; ++r)
                Gb[(size_t)(mb + r) * N_ + nn] = f2h(acc[i][j][r]);
        }
    }
}

// ---- gatherS (8-p octet, fast/slow path): S[l][p] = invn[l]*sum9 E[l+k][p+k] ----
__global__ void gatherS(const float* __restrict__ E, const float* __restrict__ invn,
                        float* __restrict__ S) {
    int wg = blockIdx.x;
    int wgid = (wg & 7) * (gridDim.x >> 3) + (wg >> 3);   // XCD chunk swizzle
    int idx = wgid * 256 + threadIdx.x;                    // BN_*LL*288 octets
    int q = idx % 288;
    int l = (idx / 288) % LL;
    int n = idx / (288 * LL);
    int p0 = q * 8;
    int li = l / WS, lj = l % WS;
    int pi = p0 / WS, pj = p0 % WS;
    const float* Eb = E + (size_t)n * LL * LL;
    float4v acc0 = {0.f, 0.f, 0.f, 0.f}, acc1 = {0.f, 0.f, 0.f, 0.f};
    bool fast = (pj >= 1) && (pj + 8 <= WS - 1);   // pj in {8..32}: all 8 lanes valid all dx
#pragma unroll
    for (int dy = -1; dy <= 1; ++dy) {
        if (li + dy < 0 || li + dy >= HS) continue;
        if (pi + dy < 0 || pi + dy >= HS) continue;
#pragma unroll
        for (int dx = -1; dx <= 1; ++dx) {
            if (lj + dx < 0 || lj + dx >= WS) continue;
            int k = dy * WS + dx;
            const float* row = &Eb[(size_t)(l + k) * LL + p0 + k];
            float4u a = *(const float4u*)row;
            float4u b = *(const float4u*)(row + 4);
            if (fast) {
                acc0 += (float4v)a;
                acc1 += (float4v)b;
            } else {
                if (pj + dx >= 0) acc0[0] += a[0];
                acc0[1] += a[1]; acc0[2] += a[2]; acc0[3] += a[3];
                acc1[0] += b[0]; acc1[1] += b[1]; acc1[2] += b[2];
                if (pj + 7 + dx < WS) acc1[3] += b[3];
            }
        }
    }
    float iv = invn[n * LL + l];
    float* dst = &S[((size_t)n * LL + l) * LL + p0];
    *(float4v*)dst = acc0 * iv;
    *(float4v*)(dst + 4) = acc1 * iv;
}

// ---- fuse (8-p octet, fast/slow path): double conv_eye + mask + x10 ----
__global__ void fuse_kernel(const float* __restrict__ S, const float* __restrict__ maskadd,
                            float* __restrict__ Sf) {
    int wg = blockIdx.x;
    int wgid = (wg & 7) * (gridDim.x >> 3) + (wg >> 3);
    int idx = wgid * 256 + threadIdx.x;                    // BN_*LL*288 octets
    int q = idx % 288;
    int l = (idx / 288) % LL;
    int n = idx / (288 * LL);
    int p0 = q * 8;
    const float* Sb = S + (size_t)n * LL * LL;
    int Tl = Tswap(l);
    int Tp0 = Tswap(p0);
    float4v acc0 = {0.f, 0.f, 0.f, 0.f}, acc1 = {0.f, 0.f, 0.f, 0.f};
#pragma unroll
    for (int d2 = -1; d2 <= 1; ++d2) {
        int fl = Tl + d2;
        if (fl < 0 || fl >= LL) continue;
        int fp0 = Tp0 + d2;
        if (fp0 >= LL) continue;
        int l2 = Tswap(fl);
        int ee = (fp0 < 0) ? 1 : 0;
        int p2b = Tswap(fp0 + 48 * ee) - ee;       // p2(e) = p2b + e, e in [0,8)
        // fast: all 8 lanes valid for all d1 taps
        bool fast = (fp0 >= 0) && (fp0 + 48 * 7 < LL) && (p2b - 1 >= 0) && (p2b + 8 < LL);
        if (fast) {
#pragma unroll
            for (int d1 = -1; d1 <= 1; ++d1) {
                int l3 = l2 + d1;
                if (l3 < 0 || l3 >= LL) continue;
                const float* row = &Sb[(size_t)l3 * LL + p2b + d1];
                float4u a = *(const float4u*)row;
                float4u b = *(const float4u*)(row + 4);
                acc0 += (float4v)a;
                acc1 += (float4v)b;
            }
        } else {
            bool lo0 = (fp0 >= 0);
            bool up1 = (fp0 + 48 < LL), up2 = (fp0 + 96 < LL), up3 = (fp0 + 144 < LL);
            bool up4 = (fp0 + 192 < LL), up5 = (fp0 + 240 < LL), up6 = (fp0 + 288 < LL);
            bool up7 = (fp0 + 336 < LL);
#pragma unroll
            for (int d1 = -1; d1 <= 1; ++d1) {
                int l3 = l2 + d1;
                if (l3 < 0 || l3 >= LL) continue;
                int pc = p2b + d1;
                const float* row = &Sb[(size_t)l3 * LL + pc];
                float4u a = *(const float4u*)row;
                float4u b = *(const float4u*)(row + 4);
                if (lo0 && pc >= 0 && pc < LL)  acc0[0] += a[0];
                if (up1 && pc + 1 < LL)         acc0[1] += a[1];
                if (up2 && pc + 2 < LL)         acc0[2] += a[2];
                if (up3 && pc + 3 < LL)         acc0[3] += a[3];
                if (up4 && pc + 4 < LL)         acc1[0] += b[0];
                if (up5 && pc + 5 < LL)         acc1[1] += b[1];
                if (up6 && pc + 6 < LL)         acc1[2] += b[2];
                if (up7 && pc + 7 < LL)         acc1[3] += b[3];
            }
        }
    }
    float madd = maskadd[n * LL + l];
    float* dst = &Sf[((size_t)n * LL + l) * LL + p0];
    float4v o0, o1;
#pragma unroll
    for (int i = 0; i < 4; ++i) { o0[i] = acc0[i] * 10.f + madd; o1[i] = acc1[i] * 10.f + madd; }
    *(float4v*)dst = o0;
    *(float4v*)(dst + 4) = o1;
}

// ---- colstat (float4): online (m,s) per column over an l-split ----
// grid (LL/256=9, NLS=32, BN_), block 256 = 64 p-quads x 4 l-rows; 18 iters/thread.
__global__ __launch_bounds__(256) void colstat_kernel(const float* __restrict__ F,
                                                      float* __restrict__ pm,
                                                      float* __restrict__ ps) {
    __shared__ float msh[4][256], ssh[4][256];
    int pb = blockIdx.x, lsp = blockIdx.y, n = blockIdx.z;
    int tq = threadIdx.x & 63;
    int tl = threadIdx.x >> 6;
    int p0 = pb * 256 + tq * 4;
    const float* Fb = F + (size_t)n * LL * LL;
    const int lspan = LL / NLS;                    // 72
    float mreg[4] = {-3e38f, -3e38f, -3e38f, -3e38f};
    float sreg[4] = {0.f, 0.f, 0.f, 0.f};
    int l_end = (lsp + 1) * lspan;
    for (int l = lsp * lspan + tl; l < l_end; l += 4) {
        float4v v = *(const float4v*)&Fb[(size_t)l * LL + p0];
#pragma unroll
        for (int i = 0; i < 4; ++i) {
            float mm = fmaxf(mreg[i], v[i]);
            sreg[i] = sreg[i] * __expf(mreg[i] - mm) + __expf(v[i] - mm);
            mreg[i] = mm;
        }
    }
#pragma unroll
    for (int i = 0; i < 4; ++i) { msh[tl][tq * 4 + i] = mreg[i]; ssh[tl][tq * 4 + i] = sreg[i]; }
    __syncthreads();
    if (tl == 0) {
#pragma unroll
        for (int i = 0; i < 4; ++i) {
            float m = msh[0][tq * 4 + i], s = ssh[0][tq * 4 + i];
#pragma unroll
            for (int r = 1; r < 4; ++r) {
                float m2 = msh[r][tq * 4 + i], s2 = ssh[r][tq * 4 + i];
                float mm = fmaxf(m, m2);
                s = s * __expf(m - mm) + s2 * __expf(m2 - mm);
                m = mm;
            }
            pm[((size_t)n * NLS + lsp) * LL + p0 + i] = m;
            ps[((size_t)n * NLS + lsp) * LL + p0 + i] = s;
        }
    }
}

// ---- merge NLS partials -> mstat[p], sinv[p] ----
__global__ void mergestat_kernel(const float* __restrict__ pm, const float* __restrict__ ps,
                                 float* __restrict__ mstat, float* __restrict__ sinv) {
    int idx = blockIdx.x * 256 + threadIdx.x;
    if (idx >= BN_ * LL) return;
    int n = idx / LL, p = idx % LL;
    float m = -3e38f, s = 0.f;
    for (int q = 0; q < NLS; ++q) {
        float m2 = pm[((size_t)n * NLS + q) * LL + p];
        float s2 = ps[((size_t)n * NLS + q) * LL + p];
        float mm = fmaxf(m, m2);
        s = s * __expf(m - mm) + s2 * __expf(m2 - mm);
        m = mm;
    }
    mstat[idx] = m;
    sinv[idx] = 1.f / s;
}

// ---- finish 64x64: att = exp(F-m)*sinv -> att_out (float4); emit f16 attT (32B) ----
__global__ __launch_bounds__(256) void finish_kernel(const float* __restrict__ F,
                                                     const float* __restrict__ mstat,
                                                     const float* __restrict__ sinv,
                                                     float* __restrict__ att,
                                                     unsigned short* __restrict__ Th) {
    __shared__ float tile[64][65];
    int n = blockIdx.z;
    int l0 = blockIdx.y * 64, p0 = blockIdx.x * 64;
    const float* Fb = F + (size_t)n * LL * LL;
    float* Ab = att + (size_t)n * LL * LL;
    int tx = threadIdx.x & 15, ty = threadIdx.x >> 4;
    float4v m4 = *(const float4v*)&mstat[n * LL + p0 + tx * 4];
    float4v s4 = *(const float4v*)&sinv[n * LL + p0 + tx * 4];
#pragma unroll
    for (int q = 0; q < 4; ++q) {
        int lr = q * 16 + ty;
        float4v v = *(const float4v*)&Fb[(size_t)(l0 + lr) * LL + p0 + tx * 4];
        float4v e;
#pragma unroll
        for (int i = 0; i < 4; ++i) e[i] = __expf(v[i] - m4[i]) * s4[i];
        *(float4v*)&Ab[(size_t)(l0 + lr) * LL + p0 + tx * 4] = e;
#pragma unroll
        for (int i = 0; i < 4; ++i) tile[lr][tx * 4 + i] = e[i];
    }
    __syncthreads();
    int pr = threadIdx.x >> 2, lq = threadIdx.x & 3;
    uint32_t u[8];
#pragma unroll
    for (int i = 0; i < 8; ++i) {
        unsigned short h0 = f2h(tile[lq * 16 + 2 * i][pr]);
        unsigned short h1 = f2h(tile[lq * 16 + 2 * i + 1][pr]);
        u[i] = (uint32_t)h0 | ((uint32_t)h1 << 16);
    }
    unsigned short* dst = &Th[((size_t)n * LL + p0 + pr) * LL + l0 + lq * 16];
    ((uint32_t*)dst)[0] = u[0]; ((uint32_t*)dst)[1] = u[1];
    ((uint32_t*)dst)[2] = u[2]; ((uint32_t*)dst)[3] = u[3];
    ((uint32_t*)dst)[4] = u[4]; ((uint32_t*)dst)[5] = u[5];
    ((uint32_t*)dst)[6] = u[6]; ((uint32_t*)dst)[7] = u[7];
}

// ---- col2im gather from f16 G[p][j] (float4-out) + overlap division ----
__global__ void col2im_kernel(const unsigned short* __restrict__ G, float* __restrict__ out) {
    int idx = blockIdx.x * 256 + threadIdx.x;
    if (idx >= BN_ * CC * HF * WF / 4) return;
    int xq = idx % (WF / 4);
    int y = (idx / (WF / 4)) % HF;
    int c = (idx / (WF / 4 * HF)) % CC;
    int n = idx / (WF / 4 * HF * CC);
    int x0 = xq * 4;
    const unsigned short* Gb = G + (size_t)n * LL * J2;
    float4v acc = {0.f, 0.f, 0.f, 0.f};
#pragma unroll
    for (int ky = 0; ky < 4; ++ky) {
        int ynum = y + 1 - ky;
        if (ynum & 1) continue;
        int iy = ynum >> 1;
        if (iy < 0 || iy >= HS) continue;
#pragma unroll
        for (int kx = 0; kx < 4; ++kx) {
#pragma unroll
            for (int e = 0; e < 4; ++e) {
                int xnum = x0 + e + 1 - kx;
                if (xnum & 1) continue;
                int ix = xnum >> 1;
                if (ix < 0 || ix >= WS) continue;
                acc[e] += h2f(Gb[(size_t)(iy * WS + ix) * J2 + c * 16 + ky * 4 + kx]);
            }
        }
    }
    float cy = (y == 0 || y == HF - 1) ? 1.f : 2.f;
    float4v o;
#pragma unroll
    for (int e = 0; e < 4; ++e) {
        int x = x0 + e;
        float cx = (x == 0 || x == WF - 1) ? 1.f : 2.f;
        o[e] = acc[e] / (cy * cx);
    }
    *(float4v*)&out[((size_t)(n * CC + c) * HF + y) * WF + x0] = o;
}

extern "C" void kernel_launch(void* const* d_in, const int* in_sizes, int n_in,
                              void* d_out, int out_size, void* d_ws, size_t ws_size,
                              hipStream_t stream) {
    const float* x       = (const float*)d_in[0];
    const float* context = (const float*)d_in[1];
    const float* mask    = (const float*)d_in[2];

    float* out = (float*)d_out;                                  // [4][96][96][96]
    float* att_region = out + (size_t)BN_ * CC * HF * WF;        // [4][2304][2304] fp32

    // workspace (bytes); proven ws_size >= 148,672,512 (exact peak).
    //  Th @0 (42,467,328) ; pm @42,467,328 (1,179,648) ; ps @43,646,976 (1,179,648) ;
    //  mstat @44,826,624 ; sinv @44,863,488 ; invn @44,900,352 ; ssum @44,937,216 ;
    //  cs/xs f16 splits @44,974,080 (7,077,888, dead after GEMM0) ends 52,051,968 ;
    //  big region @63,700,992 (84,934,656): E -> F -> RF+G ; maskadd @148,635,648.
    char* wsb = (char*)d_ws;
    const size_t ESL = (size_t)BN_ * LL * CC;      // 884,736 elements
    const size_t ERF = (size_t)BN_ * J2 * LL;      // 14,155,776
    unsigned short* Th = (unsigned short*)wsb;                    // [4][2304][2304] f16
    float* pm    = (float*)(wsb + 42467328);                      // [4][32][2304]
    float* ps    = (float*)(wsb + 43646976);
    float* mstat = (float*)(wsb + 44826624);                      // [4][2304]
    float* sinv  = (float*)(wsb + 44863488);
    float* invn  = (float*)(wsb + 44900352);
    float* ssum  = (float*)(wsb + 44937216);
    unsigned short* cs_hi = (unsigned short*)(wsb + 44974080);
    unsigned short* cs_lo = cs_hi + ESL;
    unsigned short* xs_hi = cs_lo + ESL;
    unsigned short* xs_lo = xs_hi + ESL;
    float* E = (float*)(wsb + 63700992);                          // [4][2304][2304] fp32
    float* F = (float*)(wsb + 63700992);                          // overlays E after gatherS
    unsigned short* RF = (unsigned short*)(wsb + 63700992);       // overlays F after finish
    unsigned short* G  = (unsigned short*)(wsb + 92012544);
    float* maskadd = (float*)(wsb + 148635648);
    float* S = att_region;                                        // S lives in d_out att region

    ssum_kernel<<<(BN_ * HS * WS + 255) / 256, 256, 0, stream>>>(context, ssum);
    invnmask_kernel<<<(BN_ * LL + 255) / 256, 256, 0, stream>>>(ssum, mask, invn, maskadd);

    // strided-slice channel splits (K=96 operands), both tensors in one launch
    slice_split2<<<dim3((int)(ESL / 256), 2), 256, 0, stream>>>(
        context, x, cs_hi, cs_lo, xs_hi, xs_lo);

    // GEMM0 (3-term f16 split, K=96): E[u][v] = cs . xs^T (fp32)
    gemm_split3<<<(LL / 128) * (LL / 128) * BN_, 256, 0, stream>>>(
        cs_hi, cs_lo, xs_hi, xs_lo, E, LL, LL, CC, LL / 128, LL / 128);

    // patch-sum factorization: S[l][p] = invn[l] * 9-tap diagonal gather of E
    gatherS<<<(int)((size_t)BN_ * LL * 288 / 256), 256, 0, stream>>>(E, invn, S);

    // fuse (both conv_eye passes) + mask + x10: S (d_out) -> F (ws, over dead E)
    fuse_kernel<<<(int)((size_t)BN_ * LL * 288 / 256), 256, 0, stream>>>(S, maskadd, F);

    // softmax over l: float4 column stats; finish writes att (d_out) + f16 attT
    colstat_kernel<<<dim3(LL / 256, NLS, BN_), 256, 0, stream>>>(F, pm, ps);
    mergestat_kernel<<<(BN_ * LL + 255) / 256, 256, 0, stream>>>(pm, ps, mstat, sinv);
    finish_kernel<<<dim3(LL / 64, LL / 64, BN_), 256, 0, stream>>>(F, mstat, sinv, att_region, Th);

    // raw filters f16 (F dead now; RF overlays it)
    rf_split<<<(int)(ERF / 256), 256, 0, stream>>>(context, RF);

    // GEMM2 (1-term f16, BK=64): G[p][j] = att^T . RF^T  (f16 out)
    gemm_k64<<<(J2 / 128) * (LL / 128) * BN_, 256, 0, stream>>>(
        Th, RF, G, LL, J2, LL, J2 / 128, LL / 128);

    // col2im gather + overlap normalization -> out
    col2im_kernel<<<(BN_ * CC * HF * WF / 4 + 255) / 256, 256, 0, stream>>>(G, out);
}

// Round 17
// 337.158 us; speedup vs baseline: 1.3704x; 1.3704x over previous
//
#include <hip/hip_runtime.h>
#include <stdint.h>

// Problem constants (N,C,H,W)=(4,96,96,96), half-res 48x48
#define BN_ 4
#define CC 96
#define HF 96
#define WF 96
#define HS 48
#define WS 48
#define LL 2304      // HS*WS
#define J2 1536      // CC*16 (4x4 raw filter feature dim)
#define NEG10 (-1.0e10f)
#define NLS 32       // l-splits for colstat partials (72 l each)

typedef __attribute__((ext_vector_type(8))) _Float16 half8v;
typedef __attribute__((ext_vector_type(4))) float float4v;
typedef float float4u __attribute__((ext_vector_type(4), aligned(4)));  // unaligned-capable

__device__ __forceinline__ int Tswap(int f) { return (f % 48) * 48 + f / 48; }

__device__ __forceinline__ unsigned short f2h(float f) {
    _Float16 h = (_Float16)f;
    return __builtin_bit_cast(unsigned short, h);
}
__device__ __forceinline__ float h2f(unsigned short u) {
    return (float)__builtin_bit_cast(_Float16, u);
}

typedef const __attribute__((address_space(1))) uint32_t* gas_ptr;
typedef __attribute__((address_space(3))) uint32_t* las_ptr;
__device__ __forceinline__ void gload16(const void* g, void* l) {
    __builtin_amdgcn_global_load_lds((gas_ptr)g, (las_ptr)l, 16, 0, 0);
}

// ---- channel-sum-of-squares of strided context: ssum[n][i][j] ----
__global__ void ssum_kernel(const float* __restrict__ ctx, float* __restrict__ ssum) {
    int idx = blockIdx.x * 256 + threadIdx.x;
    if (idx >= BN_ * HS * WS) return;
    int j = idx % WS, i = (idx / WS) % HS, n = idx / (WS * HS);
    float s = 0.f;
    for (int c = 0; c < CC; ++c) {
        float v = ctx[((size_t)(n * CC + c) * HF + 2 * i) * WF + 2 * j];
        s += v * v;
    }
    ssum[idx] = s;
}

// ---- merged: invn[n][l] and maskadd[n][l] ----
__global__ void invnmask_kernel(const float* __restrict__ ssum, const float* __restrict__ mask,
                                float* __restrict__ invn, float* __restrict__ maskadd) {
    int idx = blockIdx.x * 256 + threadIdx.x;
    if (idx >= BN_ * LL) return;
    int l = idx % LL, n = idx / LL;
    int i0 = l / WS, j0 = l % WS;
    float s = 0.f, ms = 0.f;
    for (int dy = -1; dy <= 1; ++dy)
        for (int dx = -1; dx <= 1; ++dx) {
            int i = i0 + dy, j = j0 + dx;
            if (i >= 0 && i < HS && j >= 0 && j < WS) {
                s += ssum[(n * HS + i) * WS + j];
                ms += mask[(size_t)n * HF * WF + (2 * i) * WF + 2 * j];
            }
        }
    invn[idx] = 1.f / fmaxf(sqrtf(s), 1e-4f);
    maskadd[idx] = (ms > 0.f) ? NEG10 : 0.f;
}

// ---- strided slice + f16 hi/lo split for BOTH tensors: dst[n][u][c] (c-major) ----
__global__ void slice_split2(const float* __restrict__ ctx, const float* __restrict__ x,
                             unsigned short* __restrict__ cs_hi, unsigned short* __restrict__ cs_lo,
                             unsigned short* __restrict__ xs_hi, unsigned short* __restrict__ xs_lo) {
    int idx = blockIdx.x * 256 + threadIdx.x;
    if (idx >= BN_ * LL * CC) return;
    const float* src = blockIdx.y ? x : ctx;
    unsigned short* hi = blockIdx.y ? xs_hi : cs_hi;
    unsigned short* lo = blockIdx.y ? xs_lo : cs_lo;
    int c = idx % CC;
    int u = (idx / CC) % LL;
    int n = idx / (CC * LL);
    int i = u / WS, j = u % WS;
    float v = src[((size_t)(n * CC + c) * HF + 2 * i) * WF + 2 * j];
    unsigned short h = f2h(v);
    hi[idx] = h;
    lo[idx] = f2h(v - h2f(h));
}

// ---- raw filter, transposed, f16: RF[n][j][l] ----
__global__ void rf_split(const float* __restrict__ ctx, unsigned short* __restrict__ hf) {
    int idx = blockIdx.x * 256 + threadIdx.x;
    if (idx >= BN_ * J2 * LL) return;
    int l = idx % LL;
    int j = (idx / LL) % J2;
    int n = idx / (LL * J2);
    int c = j >> 4, ky = (j >> 2) & 3, kx = j & 3;
    int y = 2 * (l / WS) + ky - 1;
    int x = 2 * (l % WS) + kx - 1;
    float v = 0.f;
    if (y >= 0 && y < HF && x >= 0 && x < WF)
        v = ctx[((size_t)(n * CC + c) * HF + y) * WF + x];
    hf[idx] = f2h(v);
}

// ---- f16 MFMA GEMM (TERMS=3 split, BK=32, single-buffer): C fp32 ----
__global__ __launch_bounds__(256, 4) void gemm_split3(
    const unsigned short* __restrict__ Ah_, const unsigned short* __restrict__ Al_,
    const unsigned short* __restrict__ Bh_, const unsigned short* __restrict__ Bl_,
    float* __restrict__ Cout, int M_, int N_, int K_, int nbx, int nby)
{
    __shared__ unsigned short lds[4][128][32];

    int wg = blockIdx.x;
    int wgid = (wg & 7) * (gridDim.x >> 3) + (wg >> 3);
    int bx = wgid % nbx;
    int t1 = wgid / nbx;
    int by = t1 % nby;
    int bz = t1 / nby;
    const int m0 = by * 128, n0 = bx * 128;
    const int t = threadIdx.x;

    const size_t sA = (size_t)M_ * K_, sB = (size_t)N_ * K_;
    const unsigned short* Ah = Ah_ + (size_t)bz * sA;
    const unsigned short* Al = Al_ + (size_t)bz * sA;
    const unsigned short* Bh = Bh_ + (size_t)bz * sB;
    const unsigned short* Bl = Bl_ + (size_t)bz * sB;

    const int rloc = t >> 2;
    const int sst = t & 3;
    const int kg = sst ^ ((rloc >> 1) & 3);
    const size_t offA0 = (size_t)(m0 + rloc) * K_ + kg * 8;
    const size_t offA1 = (size_t)(m0 + 64 + rloc) * K_ + kg * 8;
    const size_t offB0 = (size_t)(n0 + rloc) * K_ + kg * 8;
    const size_t offB1 = (size_t)(n0 + 64 + rloc) * K_ + kg * 8;
    const unsigned short* gp0 = Ah + offA0;
    const unsigned short* gp1 = Ah + offA1;
    const unsigned short* gp2 = Al + offA0;
    const unsigned short* gp3 = Al + offA1;
    const unsigned short* gp4 = Bh + offB0;
    const unsigned short* gp5 = Bh + offB1;
    const unsigned short* gp6 = Bl + offB0;
    const unsigned short* gp7 = Bl + offB1;
    unsigned short* lp0 = &lds[0][rloc][sst * 8];
    unsigned short* lp1 = &lds[0][64 + rloc][sst * 8];
    unsigned short* lp2 = &lds[1][rloc][sst * 8];
    unsigned short* lp3 = &lds[1][64 + rloc][sst * 8];
    unsigned short* lp4 = &lds[2][rloc][sst * 8];
    unsigned short* lp5 = &lds[2][64 + rloc][sst * 8];
    unsigned short* lp6 = &lds[3][rloc][sst * 8];
    unsigned short* lp7 = &lds[3][64 + rloc][sst * 8];

    const int lane = t & 63;
    const int w = t >> 6, wr = w >> 1, wc = w & 1;
    const int lr = lane & 15, lg = lane >> 4;

    float4v acc[4][4] = {};
    const int nt = K_ / 32;

    for (int kt = 0; kt < nt; ++kt) {
        __syncthreads();
        gload16(gp0, lp0); gload16(gp1, lp1);
        gload16(gp2, lp2); gload16(gp3, lp3);
        gload16(gp4, lp4); gload16(gp5, lp5);
        gload16(gp6, lp6); gload16(gp7, lp7);
        gp0 += 32; gp1 += 32; gp2 += 32; gp3 += 32;
        gp4 += 32; gp5 += 32; gp6 += 32; gp7 += 32;
        __syncthreads();

        half8v bh[4], bl[4];
#pragma unroll
        for (int j = 0; j < 4; ++j) {
            int row = wc * 64 + j * 16 + lr;
            int s = (lg ^ ((row >> 1) & 3)) * 8;
            bh[j] = *(const half8v*)&lds[2][row][s];
            bl[j] = *(const half8v*)&lds[3][row][s];
        }
#pragma unroll
        for (int i = 0; i < 4; ++i) {
            int row = wr * 64 + i * 16 + lr;
            int s = (lg ^ ((row >> 1) & 3)) * 8;
            half8v ah = *(const half8v*)&lds[0][row][s];
            half8v al = *(const half8v*)&lds[1][row][s];
#pragma unroll
            for (int j = 0; j < 4; ++j) {
                acc[i][j] = __builtin_amdgcn_mfma_f32_16x16x32_f16(ah, bh[j], acc[i][j], 0, 0, 0);
                acc[i][j] = __builtin_amdgcn_mfma_f32_16x16x32_f16(ah, bl[j], acc[i][j], 0, 0, 0);
                acc[i][j] = __builtin_amdgcn_mfma_f32_16x16x32_f16(al, bh[j], acc[i][j], 0, 0, 0);
            }
        }
    }

    float* Cb = Cout + (size_t)bz * M_ * N_;
#pragma unroll
    for (int i = 0; i < 4; ++i) {
        int mb = m0 + wr * 64 + i * 16 + lg * 4;
#pragma unroll
        for (int j = 0; j < 4; ++j) {
            int nn = n0 + wc * 64 + j * 16 + lr;
#pragma unroll
            for (int r = 0; r < 4; ++r)
                Cb[(size_t)(mb + r) * N_ + nn] = acc[i][j][r];
        }
    }
}

// ---- f16 MFMA GEMM (1-term, BK=64, single-buffer 1-phase): C f16 ----
__global__ __launch_bounds__(256, 4) void gemm_k64(
    const unsigned short* __restrict__ Ah_, const unsigned short* __restrict__ Bh_,
    unsigned short* __restrict__ Cout, int M_, int N_, int K_, int nbx, int nby)
{
    __shared__ unsigned short lds[2][128][64];

    int wg = blockIdx.x;
    int wgid = (wg & 7) * (gridDim.x >> 3) + (wg >> 3);
    int bx = wgid % nbx;
    int t1 = wgid / nbx;
    int by = t1 % nby;
    int bz = t1 / nby;
    const int m0 = by * 128, n0 = bx * 128;
    const int t = threadIdx.x;

    const unsigned short* Ah = Ah_ + (size_t)bz * M_ * K_;
    const unsigned short* Bh = Bh_ + (size_t)bz * N_ * K_;

    const unsigned short* gpA[4];
    const unsigned short* gpB[4];
    int lo[4];
#pragma unroll
    for (int rep = 0; rep < 4; ++rep) {
        int slot = t + rep * 256;
        int row = slot >> 3, sc = slot & 7;
        int kg = sc ^ (row & 7);                   // pre-swizzled global source
        gpA[rep] = Ah + (size_t)(m0 + row) * K_ + kg * 8;
        gpB[rep] = Bh + (size_t)(n0 + row) * K_ + kg * 8;
        lo[rep] = row * 64 + sc * 8;               // linear LDS dest (shorts)
    }

    const int lane = t & 63;
    const int w = t >> 6, wr = w >> 1, wc = w & 1;
    const int lr = lane & 15, lg = lane >> 4;

    float4v acc[4][4] = {};
    const int nt = K_ / 64;
    unsigned short* LA = &lds[0][0][0];
    unsigned short* LB = &lds[1][0][0];

    for (int kt = 0; kt < nt; ++kt) {
        __syncthreads();
#pragma unroll
        for (int rep = 0; rep < 4; ++rep) {
            gload16(gpA[rep], LA + lo[rep]);
            gload16(gpB[rep], LB + lo[rep]);
            gpA[rep] += 64; gpB[rep] += 64;
        }
        __syncthreads();
#pragma unroll
        for (int kk = 0; kk < 2; ++kk) {
            half8v bh[4];
#pragma unroll
            for (int j = 0; j < 4; ++j) {
                int row = wc * 64 + j * 16 + lr;
                int sc = (kk * 4 + lg) ^ (row & 7);    // same involution on read side
                bh[j] = *(const half8v*)&lds[1][row][sc * 8];
            }
#pragma unroll
            for (int i = 0; i < 4; ++i) {
                int row = wr * 64 + i * 16 + lr;
                int sc = (kk * 4 + lg) ^ (row & 7);
                half8v ah = *(const half8v*)&lds[0][row][sc * 8];
#pragma unroll
                for (int j = 0; j < 4; ++j)
                    acc[i][j] = __builtin_amdgcn_mfma_f32_16x16x32_f16(ah, bh[j], acc[i][j], 0, 0, 0);
            }
        }
    }

    unsigned short* Gb = Cout + (size_t)bz * M_ * N_;
#pragma unroll
    for (int i = 0; i < 4; ++i) {
        int mb = m0 + wr * 64 + i * 16 + lg * 4;
#pragma unroll
        for (int j = 0; j < 4; ++j) {
            int nn = n0 + wc * 64 + j * 16 + lr;
#pragma unroll
            for (int r = 0; r < 4; ++r)
                Gb[(size_t)(mb + r) * N_ + nn] = f2h(acc[i][j][r]);
        }
    }
}

// ---- gatherS (8-p octet, fast/slow path): S[l][p] = invn[l]*sum9 E[l+k][p+k] ----
__global__ void gatherS(const float* __restrict__ E, const float* __restrict__ invn,
                        float* __restrict__ S) {
    int wg = blockIdx.x;
    int wgid = (wg & 7) * (gridDim.x >> 3) + (wg >> 3);   // XCD chunk swizzle
    int idx = wgid * 256 + threadIdx.x;                    // BN_*LL*288 octets
    int q = idx % 288;
    int l = (idx / 288) % LL;
    int n = idx / (288 * LL);
    int p0 = q * 8;
    int li = l / WS, lj = l % WS;
    int pi = p0 / WS, pj = p0 % WS;
    const float* Eb = E + (size_t)n * LL * LL;
    float4v acc0 = {0.f, 0.f, 0.f, 0.f}, acc1 = {0.f, 0.f, 0.f, 0.f};
    bool fast = (pj >= 1) && (pj + 8 <= WS - 1);   // all 8 lanes valid for all dx
#pragma unroll
    for (int dy = -1; dy <= 1; ++dy) {
        if (li + dy < 0 || li + dy >= HS) continue;
        if (pi + dy < 0 || pi + dy >= HS) continue;
#pragma unroll
        for (int dx = -1; dx <= 1; ++dx) {
            if (lj + dx < 0 || lj + dx >= WS) continue;
            int k = dy * WS + dx;
            const float* row = &Eb[(size_t)(l + k) * LL + p0 + k];
            float4u a = *(const float4u*)row;
            float4u b = *(const float4u*)(row + 4);
            if (fast) {
                acc0 += (float4v)a;
                acc1 += (float4v)b;
            } else {
                if (pj + dx >= 0) acc0[0] += a[0];
                acc0[1] += a[1]; acc0[2] += a[2]; acc0[3] += a[3];
                acc1[0] += b[0]; acc1[1] += b[1]; acc1[2] += b[2];
                if (pj + 7 + dx < WS) acc1[3] += b[3];
            }
        }
    }
    float iv = invn[n * LL + l];
    float* dst = &S[((size_t)n * LL + l) * LL + p0];
    *(float4v*)dst = acc0 * iv;
    *(float4v*)(dst + 4) = acc1 * iv;
}

// ---- fuse (8-p octet, fast/slow path): double conv_eye + mask + x10 ----
__global__ void fuse_kernel(const float* __restrict__ S, const float* __restrict__ maskadd,
                            float* __restrict__ Sf) {
    int wg = blockIdx.x;
    int wgid = (wg & 7) * (gridDim.x >> 3) + (wg >> 3);
    int idx = wgid * 256 + threadIdx.x;                    // BN_*LL*288 octets
    int q = idx % 288;
    int l = (idx / 288) % LL;
    int n = idx / (288 * LL);
    int p0 = q * 8;
    const float* Sb = S + (size_t)n * LL * LL;
    int Tl = Tswap(l);
    int Tp0 = Tswap(p0);
    float4v acc0 = {0.f, 0.f, 0.f, 0.f}, acc1 = {0.f, 0.f, 0.f, 0.f};
#pragma unroll
    for (int d2 = -1; d2 <= 1; ++d2) {
        int fl = Tl + d2;
        if (fl < 0 || fl >= LL) continue;
        int fp0 = Tp0 + d2;
        if (fp0 >= LL) continue;
        int l2 = Tswap(fl);
        int ee = (fp0 < 0) ? 1 : 0;
        int p2b = Tswap(fp0 + 48 * ee) - ee;       // p2(e) = p2b + e, e in [0,8)
        bool fast = (fp0 >= 0) && (fp0 + 48 * 7 < LL) && (p2b - 1 >= 0) && (p2b + 8 < LL);
        if (fast) {
#pragma unroll
            for (int d1 = -1; d1 <= 1; ++d1) {
                int l3 = l2 + d1;
                if (l3 < 0 || l3 >= LL) continue;
                const float* row = &Sb[(size_t)l3 * LL + p2b + d1];
                float4u a = *(const float4u*)row;
                float4u b = *(const float4u*)(row + 4);
                acc0 += (float4v)a;
                acc1 += (float4v)b;
            }
        } else {
            bool lo0 = (fp0 >= 0);
            bool up1 = (fp0 + 48 < LL), up2 = (fp0 + 96 < LL), up3 = (fp0 + 144 < LL);
            bool up4 = (fp0 + 192 < LL), up5 = (fp0 + 240 < LL), up6 = (fp0 + 288 < LL);
            bool up7 = (fp0 + 336 < LL);
#pragma unroll
            for (int d1 = -1; d1 <= 1; ++d1) {
                int l3 = l2 + d1;
                if (l3 < 0 || l3 >= LL) continue;
                int pc = p2b + d1;
                const float* row = &Sb[(size_t)l3 * LL + pc];
                float4u a = *(const float4u*)row;
                float4u b = *(const float4u*)(row + 4);
                if (lo0 && pc >= 0 && pc < LL)  acc0[0] += a[0];
                if (up1 && pc + 1 < LL)         acc0[1] += a[1];
                if (up2 && pc + 2 < LL)         acc0[2] += a[2];
                if (up3 && pc + 3 < LL)         acc0[3] += a[3];
                if (up4 && pc + 4 < LL)         acc1[0] += b[0];
                if (up5 && pc + 5 < LL)         acc1[1] += b[1];
                if (up6 && pc + 6 < LL)         acc1[2] += b[2];
                if (up7 && pc + 7 < LL)         acc1[3] += b[3];
            }
        }
    }
    float madd = maskadd[n * LL + l];
    float* dst = &Sf[((size_t)n * LL + l) * LL + p0];
    float4v o0, o1;
#pragma unroll
    for (int i = 0; i < 4; ++i) { o0[i] = acc0[i] * 10.f + madd; o1[i] = acc1[i] * 10.f + madd; }
    *(float4v*)dst = o0;
    *(float4v*)(dst + 4) = o1;
}

// ---- colstat (float4): online (m,s) per column over an l-split ----
__global__ __launch_bounds__(256) void colstat_kernel(const float* __restrict__ F,
                                                      float* __restrict__ pm,
                                                      float* __restrict__ ps) {
    __shared__ float msh[4][256], ssh[4][256];
    int pb = blockIdx.x, lsp = blockIdx.y, n = blockIdx.z;
    int tq = threadIdx.x & 63;
    int tl = threadIdx.x >> 6;
    int p0 = pb * 256 + tq * 4;
    const float* Fb = F + (size_t)n * LL * LL;
    const int lspan = LL / NLS;                    // 72
    float mreg[4] = {-3e38f, -3e38f, -3e38f, -3e38f};
    float sreg[4] = {0.f, 0.f, 0.f, 0.f};
    int l_end = (lsp + 1) * lspan;
    for (int l = lsp * lspan + tl; l < l_end; l += 4) {
        float4v v = *(const float4v*)&Fb[(size_t)l * LL + p0];
#pragma unroll
        for (int i = 0; i < 4; ++i) {
            float mm = fmaxf(mreg[i], v[i]);
            sreg[i] = sreg[i] * __expf(mreg[i] - mm) + __expf(v[i] - mm);
            mreg[i] = mm;
        }
    }
#pragma unroll
    for (int i = 0; i < 4; ++i) { msh[tl][tq * 4 + i] = mreg[i]; ssh[tl][tq * 4 + i] = sreg[i]; }
    __syncthreads();
    if (tl == 0) {
#pragma unroll
        for (int i = 0; i < 4; ++i) {
            float m = msh[0][tq * 4 + i], s = ssh[0][tq * 4 + i];
#pragma unroll
            for (int r = 1; r < 4; ++r) {
                float m2 = msh[r][tq * 4 + i], s2 = ssh[r][tq * 4 + i];
                float mm = fmaxf(m, m2);
                s = s * __expf(m - mm) + s2 * __expf(m2 - mm);
                m = mm;
            }
            pm[((size_t)n * NLS + lsp) * LL + p0 + i] = m;
            ps[((size_t)n * NLS + lsp) * LL + p0 + i] = s;
        }
    }
}

// ---- merge NLS partials -> mstat[p], sinv[p] ----
__global__ void mergestat_kernel(const float* __restrict__ pm, const float* __restrict__ ps,
                                 float* __restrict__ mstat, float* __restrict__ sinv) {
    int idx = blockIdx.x * 256 + threadIdx.x;
    if (idx >= BN_ * LL) return;
    int n = idx / LL, p = idx % LL;
    float m = -3e38f, s = 0.f;
    for (int q = 0; q < NLS; ++q) {
        float m2 = pm[((size_t)n * NLS + q) * LL + p];
        float s2 = ps[((size_t)n * NLS + q) * LL + p];
        float mm = fmaxf(m, m2);
        s = s * __expf(m - mm) + s2 * __expf(m2 - mm);
        m = mm;
    }
    mstat[idx] = m;
    sinv[idx] = 1.f / s;
}

// ---- finish 64x64: att = exp(F-m)*sinv -> att_out (float4); emit f16 attT (32B) ----
__global__ __launch_bounds__(256) void finish_kernel(const float* __restrict__ F,
                                                     const float* __restrict__ mstat,
                                                     const float* __restrict__ sinv,
                                                     float* __restrict__ att,
                                                     unsigned short* __restrict__ Th) {
    __shared__ float tile[64][65];
    int n = blockIdx.z;
    int l0 = blockIdx.y * 64, p0 = blockIdx.x * 64;
    const float* Fb = F + (size_t)n * LL * LL;
    float* Ab = att + (size_t)n * LL * LL;
    int tx = threadIdx.x & 15, ty = threadIdx.x >> 4;
    float4v m4 = *(const float4v*)&mstat[n * LL + p0 + tx * 4];
    float4v s4 = *(const float4v*)&sinv[n * LL + p0 + tx * 4];
#pragma unroll
    for (int q = 0; q < 4; ++q) {
        int lr = q * 16 + ty;
        float4v v = *(const float4v*)&Fb[(size_t)(l0 + lr) * LL + p0 + tx * 4];
        float4v e;
#pragma unroll
        for (int i = 0; i < 4; ++i) e[i] = __expf(v[i] - m4[i]) * s4[i];
        *(float4v*)&Ab[(size_t)(l0 + lr) * LL + p0 + tx * 4] = e;
#pragma unroll
        for (int i = 0; i < 4; ++i) tile[lr][tx * 4 + i] = e[i];
    }
    __syncthreads();
    int pr = threadIdx.x >> 2, lq = threadIdx.x & 3;
    uint32_t u[8];
#pragma unroll
    for (int i = 0; i < 8; ++i) {
        unsigned short h0 = f2h(tile[lq * 16 + 2 * i][pr]);
        unsigned short h1 = f2h(tile[lq * 16 + 2 * i + 1][pr]);
        u[i] = (uint32_t)h0 | ((uint32_t)h1 << 16);
    }
    unsigned short* dst = &Th[((size_t)n * LL + p0 + pr) * LL + l0 + lq * 16];
    ((uint32_t*)dst)[0] = u[0]; ((uint32_t*)dst)[1] = u[1];
    ((uint32_t*)dst)[2] = u[2]; ((uint32_t*)dst)[3] = u[3];
    ((uint32_t*)dst)[4] = u[4]; ((uint32_t*)dst)[5] = u[5];
    ((uint32_t*)dst)[6] = u[6]; ((uint32_t*)dst)[7] = u[7];
}

// ---- col2im gather from f16 G[p][j] + overlap division (scalar, lane-coalesced) ----
__global__ void col2im_kernel(const unsigned short* __restrict__ G, float* __restrict__ out) {
    int idx = blockIdx.x * 256 + threadIdx.x;
    if (idx >= BN_ * CC * HF * WF) return;
    int x = idx % WF;
    int y = (idx / WF) % HF;
    int c = (idx / (WF * HF)) % CC;
    int n = idx / (WF * HF * CC);
    const unsigned short* Gb = G + (size_t)n * LL * J2;
    float acc = 0.f;
#pragma unroll
    for (int ky = 0; ky < 4; ++ky) {
        int ynum = y + 1 - ky;
        if (ynum & 1) continue;
        int iy = ynum >> 1;
        if (iy < 0 || iy >= HS) continue;
#pragma unroll
        for (int kx = 0; kx < 4; ++kx) {
            int xnum = x + 1 - kx;
            if (xnum & 1) continue;
            int ix = xnum >> 1;
            if (ix < 0 || ix >= WS) continue;
            acc += h2f(Gb[(size_t)(iy * WS + ix) * J2 + c * 16 + ky * 4 + kx]);
        }
    }
    float cy = (y == 0 || y == HF - 1) ? 1.f : 2.f;
    float cx = (x == 0 || x == WF - 1) ? 1.f : 2.f;
    out[idx] = acc / (cy * cx);
}

extern "C" void kernel_launch(void* const* d_in, const int* in_sizes, int n_in,
                              void* d_out, int out_size, void* d_ws, size_t ws_size,
                              hipStream_t stream) {
    const float* x       = (const float*)d_in[0];
    const float* context = (const float*)d_in[1];
    const float* mask    = (const float*)d_in[2];

    float* out = (float*)d_out;                                  // [4][96][96][96]
    float* att_region = out + (size_t)BN_ * CC * HF * WF;        // [4][2304][2304] fp32

    // workspace (bytes); proven ws_size >= 148,672,512 (exact peak).
    //  Th @0 (42,467,328) ; pm @42,467,328 (1,179,648) ; ps @43,646,976 (1,179,648) ;
    //  mstat @44,826,624 ; sinv @44,863,488 ; invn @44,900,352 ; ssum @44,937,216 ;
    //  cs/xs f16 splits @44,974,080 (7,077,888, dead after GEMM0) ends 52,051,968 ;
    //  big region @63,700,992 (84,934,656): E -> F -> RF+G ; maskadd @148,635,648.
    char* wsb = (char*)d_ws;
    const size_t ESL = (size_t)BN_ * LL * CC;      // 884,736 elements
    const size_t ERF = (size_t)BN_ * J2 * LL;      // 14,155,776
    unsigned short* Th = (unsigned short*)wsb;                    // [4][2304][2304] f16
    float* pm    = (float*)(wsb + 42467328);                      // [4][32][2304]
    float* ps    = (float*)(wsb + 43646976);
    float* mstat = (float*)(wsb + 44826624);                      // [4][2304]
    float* sinv  = (float*)(wsb + 44863488);
    float* invn  = (float*)(wsb + 44900352);
    float* ssum  = (float*)(wsb + 44937216);
    unsigned short* cs_hi = (unsigned short*)(wsb + 44974080);
    unsigned short* cs_lo = cs_hi + ESL;
    unsigned short* xs_hi = cs_lo + ESL;
    unsigned short* xs_lo = xs_hi + ESL;
    float* E = (float*)(wsb + 63700992);                          // [4][2304][2304] fp32
    float* F = (float*)(wsb + 63700992);                          // overlays E after gatherS
    unsigned short* RF = (unsigned short*)(wsb + 63700992);       // overlays F after finish
    unsigned short* G  = (unsigned short*)(wsb + 92012544);
    float* maskadd = (float*)(wsb + 148635648);
    float* S = att_region;                                        // S lives in d_out att region

    ssum_kernel<<<(BN_ * HS * WS + 255) / 256, 256, 0, stream>>>(context, ssum);
    invnmask_kernel<<<(BN_ * LL + 255) / 256, 256, 0, stream>>>(ssum, mask, invn, maskadd);

    // strided-slice channel splits (K=96 operands), both tensors in one launch
    slice_split2<<<dim3((int)(ESL / 256), 2), 256, 0, stream>>>(
        context, x, cs_hi, cs_lo, xs_hi, xs_lo);

    // GEMM0 (3-term f16 split, K=96): E[u][v] = cs . xs^T (fp32)
    gemm_split3<<<(LL / 128) * (LL / 128) * BN_, 256, 0, stream>>>(
        cs_hi, cs_lo, xs_hi, xs_lo, E, LL, LL, CC, LL / 128, LL / 128);

    // patch-sum factorization: S[l][p] = invn[l] * 9-tap diagonal gather of E
    gatherS<<<(int)((size_t)BN_ * LL * 288 / 256), 256, 0, stream>>>(E, invn, S);

    // fuse (both conv_eye passes) + mask + x10: S (d_out) -> F (ws, over dead E)
    fuse_kernel<<<(int)((size_t)BN_ * LL * 288 / 256), 256, 0, stream>>>(S, maskadd, F);

    // softmax over l: float4 column stats; finish writes att (d_out) + f16 attT
    colstat_kernel<<<dim3(LL / 256, NLS, BN_), 256, 0, stream>>>(F, pm, ps);
    mergestat_kernel<<<(BN_ * LL + 255) / 256, 256, 0, stream>>>(pm, ps, mstat, sinv);
    finish_kernel<<<dim3(LL / 64, LL / 64, BN_), 256, 0, stream>>>(F, mstat, sinv, att_region, Th);

    // raw filters f16 (F dead now; RF overlays it)
    rf_split<<<(int)(ERF / 256), 256, 0, stream>>>(context, RF);

    // GEMM2 (1-term f16, BK=64): G[p][j] = att^T . RF^T  (f16 out)
    gemm_k64<<<(J2 / 128) * (LL / 128) * BN_, 256, 0, stream>>>(
        Th, RF, G, LL, J2, LL, J2 / 128, LL / 128);

    // col2im gather + overlap normalization -> out
    col2im_kernel<<<(BN_ * CC * HF * WF + 255) / 256, 256, 0, stream>>>(G, out);
}